// Round 1
// 152.440 us; speedup vs baseline: 1.0182x; 1.0182x over previous
//
#include <hip/hip_runtime.h>
#include <hip/hip_bf16.h>

// y_i = x_i^T Q x_i + b^T x_i + c ; N=16384, D=1024, fp32.
// Round 5: occupancy restructure. Previous round: grid 256 = 1 block/CU =
// 2 waves/SIMD -> latency-bound (MfmaUtil 17%, VALUBusy 17%, HBM 33%,
// Occupancy 18%). Now: row-split 64 -> grid 512 = 2 blocks/CU (4 waves/
// SIMD). Each wave owns 32 rows (A shrinks to 64 AGPRs, fits (512,2)
// 256-reg budget with headroom). 32 Q-cols staged per round (2 B-frags
// per barrier) -> 16 barriers instead of 32; MFMA loop keeps 4
// independent chains (2 subtiles x 2 row-groups). K-split 4 / col-half 2
// unchanged -> same HBM traffic. Co-resident blocks b, b+256 share seg
// (same Q chunk) -> L2-friendly staging.

#define DD 1024
#define KH 256           // K per block (K-split 4)
#define KSTEP 8          // KH/32 MFMA k-steps per round
#define NROUND 16        // staging rounds per block (32 cols each)
#define LDS_ROW 264      // shorts: 256 + 8 pad

typedef short v8s __attribute__((ext_vector_type(8)));
typedef float v4f __attribute__((ext_vector_type(4)));

__device__ __forceinline__ short f2b(float f) {
    union { __hip_bfloat16 h; short s; } u;
    u.h = __float2bfloat16(f);
    return u.s;
}

__global__ __launch_bounds__(512, 2)
void quad_kernel(const float* __restrict__ x, const float* __restrict__ Q,
                 const float* __restrict__ bvec, const float* __restrict__ cptr,
                 float* __restrict__ y)
{
    __shared__ short lq[2][32 * LDS_ROW];   // 2 x 16.5 KB staging buffers

    const int tid  = threadIdx.x;
    const int lane = tid & 63;
    const int wave = tid >> 6;
    const int quad = lane >> 4;
    const int l15  = lane & 15;

    const int seg  = blockIdx.x & 7;     // kq*2 + cs
    const int rblk = blockIdx.x >> 3;    // 0..63
    const int kq   = seg >> 1;           // K quarter 0..3
    const int cs   = seg & 1;            // column half 0..1

    const int row_base = rblk * 256 + wave * 32;   // 32 rows per wave
    const int kofs     = kq * KH;
    const int col_base = cs * 512;

    // ---- Phase 1: A = x[32 rows][kofs..kofs+256) bf16 frags in AGPRs ----
    // A layout (16x16x32): m = lane&15, k = quad*8 + j (8 contiguous bf16)
    v8s a[2][KSTEP];
    #pragma unroll
    for (int g = 0; g < 2; ++g) {
        const float* xr = x + (size_t)(row_base + g * 16 + l15) * DD + kofs + quad * 8;
        #pragma unroll
        for (int s = 0; s < KSTEP; ++s) {
            const float4 f0 = *(const float4*)(xr + s * 32);
            const float4 f1 = *(const float4*)(xr + s * 32 + 4);
            v8s t;
            t[0]=f2b(f0.x); t[1]=f2b(f0.y); t[2]=f2b(f0.z); t[3]=f2b(f0.w);
            t[4]=f2b(f1.x); t[5]=f2b(f1.y); t[6]=f2b(f1.z); t[7]=f2b(f1.w);
            a[g][s] = t;
            asm volatile("" : "+a"(a[g][s]));   // force AGPR residency
        }
    }

    // ---- Staging map: round = 32 Qrows x 256 floats = 2048 float4 / 512 thr
    int s_nn[4], s_k4[4];
    #pragma unroll
    for (int i = 0; i < 4; ++i) {
        const int idx = tid + i * 512;
        s_nn[i] = idx >> 6;        // 0..31 (Q row within round)
        s_k4[i] = idx & 63;        // float4 within KH
    }

    // prefetch round 0
    float4 pf[4];
    #pragma unroll
    for (int i = 0; i < 4; ++i)
        pf[i] = *(const float4*)(Q + (size_t)(col_base + s_nn[i]) * DD + kofs + s_k4[i] * 4);

    float acc[2][4];
    #pragma unroll
    for (int g = 0; g < 2; ++g)
        #pragma unroll
        for (int r = 0; r < 4; ++r) acc[g][r] = 0.f;

    for (int t = 0; t < NROUND; ++t) {
        // store staged round (fp32 -> bf16) into buf t&1
        short* dst = &lq[t & 1][0];
        #pragma unroll
        for (int i = 0; i < 4; ++i) {
            const float4 f = pf[i];
            short4 s;
            s.x=f2b(f.x); s.y=f2b(f.y); s.z=f2b(f.z); s.w=f2b(f.w);
            *(short4*)&dst[s_nn[i] * LDS_ROW + s_k4[i] * 4] = s;
        }
        __syncthreads();

        // next round's prefetch AFTER the barrier: in flight across MFMA
        if (t + 1 < NROUND) {
            #pragma unroll
            for (int i = 0; i < 4; ++i)
                pf[i] = *(const float4*)(Q + (size_t)(col_base + (t + 1) * 32 + s_nn[i]) * DD + kofs + s_k4[i] * 4);
        }

        // fused-dot operands for this round's 32 columns
        const int n0 = col_base + t * 32 + l15;
        const float bn0 = (kq == 0) ? bvec[n0]      : 0.f;
        const float bn1 = (kq == 0) ? bvec[n0 + 16] : 0.f;
        float xv[2][2][4];
        {
            const float* xc = x + (size_t)(row_base + quad * 4) * DD + n0;
            #pragma unroll
            for (int nt = 0; nt < 2; ++nt)
                #pragma unroll
                for (int g = 0; g < 2; ++g)
                    #pragma unroll
                    for (int r = 0; r < 4; ++r)
                        xv[nt][g][r] = xc[(size_t)(g * 16 + r) * DD + nt * 16];
        }

        // MFMA: 2 col-subtiles x 2 row-groups = 4 independent chains
        v4f cf[2][2];
        #pragma unroll
        for (int nt = 0; nt < 2; ++nt)
            #pragma unroll
            for (int g = 0; g < 2; ++g) cf[nt][g] = (v4f){0.f, 0.f, 0.f, 0.f};
        const short* bp = &lq[t & 1][l15 * LDS_ROW + quad * 8];
        #pragma unroll
        for (int s = 0; s < KSTEP; ++s) {
            const v8s b0 = *(const v8s*)(bp + s * 32);
            const v8s b1 = *(const v8s*)(bp + 16 * LDS_ROW + s * 32);
            #pragma unroll
            for (int g = 0; g < 2; ++g) {
                cf[0][g] = __builtin_amdgcn_mfma_f32_16x16x32_bf16(a[g][s], b0, cf[0][g], 0, 0, 0);
                cf[1][g] = __builtin_amdgcn_mfma_f32_16x16x32_bf16(a[g][s], b1, cf[1][g], 0, 0, 0);
            }
        }

        // fused dot: C layout col = lane&15, row = quad*4 + reg
        #pragma unroll
        for (int g = 0; g < 2; ++g)
            #pragma unroll
            for (int r = 0; r < 4; ++r)
                acc[g][r] += (cf[0][g][r] + bn0) * xv[0][g][r]
                           + (cf[1][g][r] + bn1) * xv[1][g][r];
    }

    // ---- reduce across the 16 lanes of each quad, atomic into y ----
    const float cc = (seg == 0) ? cptr[0] : 0.f;  // c added once per row
    #pragma unroll
    for (int g = 0; g < 2; ++g) {
        #pragma unroll
        for (int r = 0; r < 4; ++r) {
            float v = acc[g][r];
            v += __shfl_xor(v, 1); v += __shfl_xor(v, 2);
            v += __shfl_xor(v, 4); v += __shfl_xor(v, 8);
            if (l15 == 0)
                atomicAdd(&y[row_base + g * 16 + quad * 4 + r], v + cc);
        }
    }
}

extern "C" void kernel_launch(void* const* d_in, const int* in_sizes, int n_in,
                              void* d_out, int out_size, void* d_ws, size_t ws_size,
                              hipStream_t stream)
{
    const float* x = (const float*)d_in[0];
    const float* Q = (const float*)d_in[1];
    const float* b = (const float*)d_in[2];
    const float* c = (const float*)d_in[3];
    float* y = (float*)d_out;

    hipMemsetAsync(y, 0, (size_t)out_size * sizeof(float), stream);
    quad_kernel<<<dim3(512), dim3(512), 0, stream>>>(x, Q, b, c, y);
}